// Round 3
// baseline (252.380 us; speedup 1.0000x reference)
//
#include <hip/hip_runtime.h>
#include <hip/hip_bf16.h>
#include <cstddef>
#include <cstdint>

#define CH_HW 4096   // 64*64

typedef __bf16  bf16x8  __attribute__((ext_vector_type(8)));
typedef float   f32x4   __attribute__((ext_vector_type(4)));
typedef unsigned int u32x4 __attribute__((ext_vector_type(4)));

// d_ws layout:
//   [0, WF_BYTES)                      packed bf16 offset-conv weights
//   [WF_BYTES, +OFFW_BYTES)            bf16 offset field
//   [WF_BYTES+OFFW_BYTES, +DWP_BYTES)  packed f32 deform weights [g][ck][o]
#define WF_ELEMS 331776                 // 72 ks * 9 nt * 64 lane * 8
#define WF_BYTES (WF_ELEMS * 2)
#define OFFW_BYTES (4u * 144u * CH_HW * 2u)   // 4,718,592
#define DWP_ELEMS (8 * 288 * 32)        // 73728
// total ~5.68 MB (< 9.44 MB proven available)

// ---------------------------------------------------------------------------
// Kernel 0a: repack offset_w (144,256,3,3) f32 -> MFMA B-fragment stream bf16
// ---------------------------------------------------------------------------
__global__ __launch_bounds__(256) void repack_w(const float* __restrict__ ow,
                                                __hip_bfloat16* __restrict__ wf)
{
    const int t = blockIdx.x * 256 + threadIdx.x;
    if (t >= WF_ELEMS) return;
    const int j    = t & 7;
    const int lane = (t >> 3) & 63;
    const int tmp  = t >> 9;         // ks*9 + nt
    const int nt   = tmp % 9;
    const int ks   = tmp / 9;
    const int tap  = ks >> 3, icb = ks & 7;
    const int oc   = nt * 16 + (lane & 15);
    const int ic   = icb * 32 + (lane >> 4) * 8 + j;
    wf[t] = __float2bfloat16(ow[(size_t)oc * 2304 + ic * 9 + tap]);
}

// ---------------------------------------------------------------------------
// Kernel 0b: repack deform_w (256,32,3,3) -> dwp[g][c*9+k][o]  (o contiguous)
// ---------------------------------------------------------------------------
__global__ __launch_bounds__(256) void repack_dw(const float* __restrict__ dw,
                                                 float* __restrict__ dwp)
{
    const int t = blockIdx.x * 256 + threadIdx.x;
    if (t >= DWP_ELEMS) return;
    const int g  = t / 9216;
    const int r  = t % 9216;
    const int ck = r >> 5;
    const int o  = r & 31;
    dwp[t] = dw[(size_t)(g * 32 + o) * 288 + ck];
}

// ---------------------------------------------------------------------------
// Kernel 1: offset conv implicit-GEMM MFMA. 512 blocks: (b, hrow, N-half).
// half0: nt 0..4 (oc 0..79), half1: nt 5..8 (oc 80..143). 2 blocks/CU.
// ---------------------------------------------------------------------------
__device__ __forceinline__ void stageA_load(const float* __restrict__ xb,
                                            int hrow, int m, int kc, int ks,
                                            float av[8])
{
    const int tap = ks >> 3, icb = ks & 7;
    const int dy = tap / 3 - 1, dx = tap % 3 - 1;
    const int sh = hrow + dy, sw = m + dx;
    const float msk = (sh >= 0 && sh < 64 && sw >= 0 && sw < 64) ? 1.f : 0.f;
    const int shc = min(max(sh, 0), 63), swc = min(max(sw, 0), 63);
    const float* p = xb + (size_t)(icb * 32 + kc * 8) * CH_HW + (shc << 6) + swc;
#pragma unroll
    for (int j = 0; j < 8; ++j) av[j] = p[(size_t)j * CH_HW] * msk;
}

__device__ __forceinline__ u32x4 pack_bf16x8(const float av[8]) {
    u32x4 ad;
#pragma unroll
    for (int jj = 0; jj < 4; ++jj) {
        const unsigned int lo = __builtin_bit_cast(unsigned short, __float2bfloat16(av[2 * jj]));
        const unsigned int hi = __builtin_bit_cast(unsigned short, __float2bfloat16(av[2 * jj + 1]));
        ad[jj] = lo | (hi << 16);
    }
    return ad;
}

__global__ __launch_bounds__(256) void offs_mfma(const float* __restrict__ x,
                                                 const __hip_bfloat16* __restrict__ wf,
                                                 const float* __restrict__ ob,
                                                 __hip_bfloat16* __restrict__ offw)
{
    __shared__ __align__(16) unsigned short aL[2][64][40];  // padded rows
    __shared__ __align__(16) unsigned short bL[2][2560];    // up to 5 nt tiles

    const int bid  = blockIdx.x;
    const int nh   = bid & 1;
    const int hrow = (bid >> 1) & 63;
    const int b    = bid >> 7;
    const int ntBase = nh * 5;        // 0 or 5
    const int NTLOC  = 5 - nh;        // 5 or 4
    const int tid  = threadIdx.x;
    const int lane = tid & 63, wave = tid >> 6;
    const int m    = lane;
    const int kc   = wave;

    const float* xb = x + (size_t)b * 256 * CH_HW;

    f32x4 acc[5];
#pragma unroll
    for (int q = 0; q < 5; ++q) acc[q] = (f32x4){0.f, 0.f, 0.f, 0.f};

    // prologue: stage ks=0 into buf 0
    {
        float av[8]; u32x4 bv[2];
        stageA_load(xb, hrow, m, kc, 0, av);
#pragma unroll
        for (int q = 0; q < 2; ++q) {
            const int ntl = wave + q * 4;
            if (ntl < NTLOC)
                bv[q] = *(const u32x4*)(wf + ((size_t)(ntBase + ntl) * 64 + lane) * 8);
        }
        *(u32x4*)&aL[0][m][kc * 8] = pack_bf16x8(av);
#pragma unroll
        for (int q = 0; q < 2; ++q) {
            const int ntl = wave + q * 4;
            if (ntl < NTLOC) *(u32x4*)&bL[0][ntl * 512 + lane * 8] = bv[q];
        }
    }
    __syncthreads();

    for (int ks = 0; ks < 72; ++ks) {
        const int buf = ks & 1, nbuf = buf ^ 1;
        const bool hasNext = (ks + 1) < 72;

        float av[8]; u32x4 bv[2];
        if (hasNext) {
            stageA_load(xb, hrow, m, kc, ks + 1, av);
#pragma unroll
            for (int q = 0; q < 2; ++q) {
                const int ntl = wave + q * 4;
                if (ntl < NTLOC)
                    bv[q] = *(const u32x4*)(wf + ((size_t)((ks + 1) * 9 + ntBase + ntl) * 64 + lane) * 8);
            }
        }

        const u32x4 au = *(const u32x4*)&aL[buf][wave * 16 + (lane & 15)][(lane >> 4) * 8];
        const bf16x8 afr = __builtin_bit_cast(bf16x8, au);
#pragma unroll
        for (int ntl = 0; ntl < 5; ++ntl) {
            if (ntl < NTLOC) {
                const u32x4 bu = *(const u32x4*)&bL[buf][ntl * 512 + lane * 8];
                acc[ntl] = __builtin_amdgcn_mfma_f32_16x16x32_bf16(
                    afr, __builtin_bit_cast(bf16x8, bu), acc[ntl], 0, 0, 0);
            }
        }

        if (hasNext) {
            *(u32x4*)&aL[nbuf][m][kc * 8] = pack_bf16x8(av);
#pragma unroll
            for (int q = 0; q < 2; ++q) {
                const int ntl = wave + q * 4;
                if (ntl < NTLOC) *(u32x4*)&bL[nbuf][ntl * 512 + lane * 8] = bv[q];
            }
        }
        __syncthreads();
    }

    // epilogue: col(oc)=lane&15, row(m)=(lane>>4)*4+r
    const int oc_l = lane & 15;
    const int mrow = wave * 16 + ((lane >> 4) << 2);
#pragma unroll
    for (int ntl = 0; ntl < 5; ++ntl) {
        if (ntl < NTLOC) {
            const int oc = (ntBase + ntl) * 16 + oc_l;
            const float bias = ob[oc];
            __hip_bfloat16* op = offw + ((size_t)b * 144 + oc) * CH_HW + hrow * 64 + mrow;
#pragma unroll
            for (int r = 0; r < 4; ++r)
                op[r] = __float2bfloat16(acc[ntl][r] + bias);
        }
    }
}

// ---------------------------------------------------------------------------
// Kernel 2: bilinear sampling + grouped conv. Weights via wave-uniform s_load
// (no LDS at all). 1 pixel/thread.
// ---------------------------------------------------------------------------
struct Samp { int iA, iB, iC, iD; float wA, wB, wC, wD; };

__device__ __forceinline__ Samp make_samp(float py, float px) {
    const float y0f = floorf(py), x0f = floorf(px);
    const int iy0 = (int)y0f, ix0 = (int)x0f;
    const int iy1 = iy0 + 1,  ix1 = ix0 + 1;
    const float fy1 = py - y0f, fx1 = px - x0f;
    const float fy0 = 1.f - fy1, fx0 = 1.f - fx1;
    const bool vy0 = (iy0 >= 0) & (iy0 < 64);
    const bool vy1 = (iy1 >= 0) & (iy1 < 64);
    const bool vx0 = (ix0 >= 0) & (ix0 < 64);
    const bool vx1 = (ix1 >= 0) & (ix1 < 64);
    const int cy0 = min(max(iy0, 0), 63), cy1 = min(max(iy1, 0), 63);
    const int cx0 = min(max(ix0, 0), 63), cx1 = min(max(ix1, 0), 63);
    Samp s;
    s.iA = (cy0 << 6) + cx0; s.iB = (cy0 << 6) + cx1;
    s.iC = (cy1 << 6) + cx0; s.iD = (cy1 << 6) + cx1;
    s.wA = (vy0 & vx0) ? fy0 * fx0 : 0.f;
    s.wB = (vy0 & vx1) ? fy0 * fx1 : 0.f;
    s.wC = (vy1 & vx0) ? fy1 * fx0 : 0.f;
    s.wD = (vy1 & vx1) ? fy1 * fx1 : 0.f;
    return s;
}

__global__ __launch_bounds__(256) void deform2(const float* __restrict__ x,
                                               const __hip_bfloat16* __restrict__ offw,
                                               const float* __restrict__ dwp,
                                               const float* __restrict__ db,
                                               float* __restrict__ out)
{
    const int chunk = blockIdx.x;  // 0..15
    const int g = blockIdx.y;
    const int b = blockIdx.z;
    const int tid = threadIdx.x;

    const int pix = (chunk << 8) + tid;
    const int h = pix >> 6, w = pix & 63;

    const __hip_bfloat16* offp = offw + ((size_t)b * 144 + g * 18) * CH_HW + pix;
    Samp sp[9];
#pragma unroll
    for (int k = 0; k < 9; ++k) {
        const float oy = __bfloat162float(offp[(size_t)(2 * k) * CH_HW]);
        const float ox = __bfloat162float(offp[(size_t)(2 * k + 1) * CH_HW]);
        sp[k] = make_samp((float)(h - 1 + k / 3) + oy, (float)(w - 1 + k % 3) + ox);
    }

    const float* xg = x + ((size_t)b * 256 + g * 32) * CH_HW;
    const float* wg = dwp + (size_t)g * 288 * 32;   // [c*9+k][o]

    float acc[32];
#pragma unroll
    for (int o = 0; o < 32; ++o) acc[o] = 0.f;

    for (int c = 0; c < 32; ++c) {
        const float* xc = xg + (size_t)c * CH_HW;
        float v[9];
#pragma unroll
        for (int k = 0; k < 9; ++k) {
            const Samp s = sp[k];
            v[k] = s.wA * xc[s.iA] + s.wB * xc[s.iB] +
                   s.wC * xc[s.iC] + s.wD * xc[s.iD];
        }
        const float* wc = wg + c * 288;   // wave-uniform -> s_load
#pragma unroll
        for (int k = 0; k < 9; ++k) {
#pragma unroll
            for (int o = 0; o < 32; ++o)
                acc[o] = fmaf(v[k], wc[k * 32 + o], acc[o]);
        }
    }

#pragma unroll
    for (int o = 0; o < 32; ++o) {
        float* op = out + ((size_t)b * 256 + g * 32 + o) * CH_HW;
        op[pix] = acc[o] + db[g * 32 + o];
    }
}

// ---------------------------------------------------------------------------
extern "C" void kernel_launch(void* const* d_in, const int* in_sizes, int n_in,
                              void* d_out, int out_size, void* d_ws, size_t ws_size,
                              hipStream_t stream) {
    const float* x  = (const float*)d_in[0];
    const float* ow = (const float*)d_in[1];
    const float* ob = (const float*)d_in[2];
    const float* dw = (const float*)d_in[3];
    const float* db = (const float*)d_in[4];
    float* out = (float*)d_out;

    __hip_bfloat16* wf   = (__hip_bfloat16*)d_ws;
    __hip_bfloat16* offw = (__hip_bfloat16*)((char*)d_ws + WF_BYTES);
    float*          dwp  = (float*)((char*)d_ws + WF_BYTES + OFFW_BYTES);

    repack_w<<<(WF_ELEMS + 255) / 256, 256, 0, stream>>>(ow, wf);
    repack_dw<<<(DWP_ELEMS + 255) / 256, 256, 0, stream>>>(dw, dwp);
    offs_mfma<<<512, 256, 0, stream>>>(x, wf, ob, offw);
    deform2<<<dim3(16, 8, 4), 256, 0, stream>>>(x, offw, dwp, db, out);
}

// Round 4
// 160.457 us; speedup vs baseline: 1.5729x; 1.5729x over previous
//
#include <hip/hip_runtime.h>
#include <hip/hip_bf16.h>
#include <cstddef>
#include <cstdint>

#define CH_HW 4096   // 64*64

typedef __bf16  bf16x8  __attribute__((ext_vector_type(8)));
typedef float   f32x4   __attribute__((ext_vector_type(4)));
typedef unsigned int u32x4 __attribute__((ext_vector_type(4)));

// d_ws layout:
//   [0, WF_BYTES)                     packed bf16 offset-conv weights (B-frags)
//   [WF_BYTES, +OFFW_BYTES)           bf16 offset field
//   [WF_BYTES+OFFW_BYTES, +DWB)       packed bf16 deform weights (B-frags)
#define WF_ELEMS 331776                 // 72 ks * 9 nt * 64 lane * 8
#define WF_BYTES (WF_ELEMS * 2)
#define OFFW_BYTES (4u * 144u * CH_HW * 2u)   // 4,718,592
#define DWB_ELEMS (8 * 9 * 2 * 512)     // 73728 bf16

// ---------------------------------------------------------------------------
// Kernel 0a: repack offset_w (144,256,3,3) f32 -> MFMA B-fragment stream bf16
// Wf[ks][nt][lane][j]; ks=tap*8+icb; oc=nt*16+(lane&15); ic=icb*32+(lane>>4)*8+j
// ---------------------------------------------------------------------------
__global__ __launch_bounds__(256) void repack_w(const float* __restrict__ ow,
                                                __hip_bfloat16* __restrict__ wf)
{
    const int t = blockIdx.x * 256 + threadIdx.x;
    if (t >= WF_ELEMS) return;
    const int j    = t & 7;
    const int lane = (t >> 3) & 63;
    const int tmp  = t >> 9;         // ks*9 + nt
    const int nt   = tmp % 9;
    const int ks   = tmp / 9;
    const int tap  = ks >> 3, icb = ks & 7;
    const int oc   = nt * 16 + (lane & 15);
    const int ic   = icb * 32 + (lane >> 4) * 8 + j;
    wf[t] = __float2bfloat16(ow[(size_t)oc * 2304 + ic * 9 + tap]);
}

// ---------------------------------------------------------------------------
// Kernel 0b: repack deform_w (256,32,3,3) -> B-frag stream
// dwb[((g*9+k)*2+nt)*512 + lane*8 + j] = w[g*32+nt*16+(lane&15)][ (lane>>4)*8+j ][k]
// ---------------------------------------------------------------------------
__global__ __launch_bounds__(256) void repack_dwb(const float* __restrict__ dw,
                                                  __hip_bfloat16* __restrict__ dwb)
{
    const int t = blockIdx.x * 256 + threadIdx.x;
    if (t >= DWB_ELEMS) return;
    const int j    = t & 7;
    const int lane = (t >> 3) & 63;
    const int nt   = (t >> 9) & 1;
    const int gk   = t >> 10;
    const int k    = gk % 9;
    const int g    = gk / 9;
    const int oc   = g * 32 + nt * 16 + (lane & 15);
    const int c    = (lane >> 4) * 8 + j;
    dwb[t] = __float2bfloat16(dw[(size_t)oc * 288 + c * 9 + k]);
}

// ---------------------------------------------------------------------------
// Kernel 1: offset conv implicit-GEMM MFMA (unchanged from round 3)
// ---------------------------------------------------------------------------
__device__ __forceinline__ void stageA_load(const float* __restrict__ xb,
                                            int hrow, int m, int kc, int ks,
                                            float av[8])
{
    const int tap = ks >> 3, icb = ks & 7;
    const int dy = tap / 3 - 1, dx = tap % 3 - 1;
    const int sh = hrow + dy, sw = m + dx;
    const float msk = (sh >= 0 && sh < 64 && sw >= 0 && sw < 64) ? 1.f : 0.f;
    const int shc = min(max(sh, 0), 63), swc = min(max(sw, 0), 63);
    const float* p = xb + (size_t)(icb * 32 + kc * 8) * CH_HW + (shc << 6) + swc;
#pragma unroll
    for (int j = 0; j < 8; ++j) av[j] = p[(size_t)j * CH_HW] * msk;
}

__device__ __forceinline__ u32x4 pack_bf16x8(const float av[8]) {
    u32x4 ad;
#pragma unroll
    for (int jj = 0; jj < 4; ++jj) {
        const unsigned int lo = __builtin_bit_cast(unsigned short, __float2bfloat16(av[2 * jj]));
        const unsigned int hi = __builtin_bit_cast(unsigned short, __float2bfloat16(av[2 * jj + 1]));
        ad[jj] = lo | (hi << 16);
    }
    return ad;
}

__global__ __launch_bounds__(256) void offs_mfma(const float* __restrict__ x,
                                                 const __hip_bfloat16* __restrict__ wf,
                                                 const float* __restrict__ ob,
                                                 __hip_bfloat16* __restrict__ offw)
{
    __shared__ __align__(16) unsigned short aL[2][64][40];
    __shared__ __align__(16) unsigned short bL[2][2560];

    const int bid  = blockIdx.x;
    const int nh   = bid & 1;
    const int hrow = (bid >> 1) & 63;
    const int b    = bid >> 7;
    const int ntBase = nh * 5;
    const int NTLOC  = 5 - nh;
    const int tid  = threadIdx.x;
    const int lane = tid & 63, wave = tid >> 6;
    const int m    = lane;
    const int kc   = wave;

    const float* xb = x + (size_t)b * 256 * CH_HW;

    f32x4 acc[5];
#pragma unroll
    for (int q = 0; q < 5; ++q) acc[q] = (f32x4){0.f, 0.f, 0.f, 0.f};

    {
        float av[8]; u32x4 bv[2];
        stageA_load(xb, hrow, m, kc, 0, av);
#pragma unroll
        for (int q = 0; q < 2; ++q) {
            const int ntl = wave + q * 4;
            if (ntl < NTLOC)
                bv[q] = *(const u32x4*)(wf + ((size_t)(ntBase + ntl) * 64 + lane) * 8);
        }
        *(u32x4*)&aL[0][m][kc * 8] = pack_bf16x8(av);
#pragma unroll
        for (int q = 0; q < 2; ++q) {
            const int ntl = wave + q * 4;
            if (ntl < NTLOC) *(u32x4*)&bL[0][ntl * 512 + lane * 8] = bv[q];
        }
    }
    __syncthreads();

    for (int ks = 0; ks < 72; ++ks) {
        const int buf = ks & 1, nbuf = buf ^ 1;
        const bool hasNext = (ks + 1) < 72;

        float av[8]; u32x4 bv[2];
        if (hasNext) {
            stageA_load(xb, hrow, m, kc, ks + 1, av);
#pragma unroll
            for (int q = 0; q < 2; ++q) {
                const int ntl = wave + q * 4;
                if (ntl < NTLOC)
                    bv[q] = *(const u32x4*)(wf + ((size_t)((ks + 1) * 9 + ntBase + ntl) * 64 + lane) * 8);
            }
        }

        const u32x4 au = *(const u32x4*)&aL[buf][wave * 16 + (lane & 15)][(lane >> 4) * 8];
        const bf16x8 afr = __builtin_bit_cast(bf16x8, au);
#pragma unroll
        for (int ntl = 0; ntl < 5; ++ntl) {
            if (ntl < NTLOC) {
                const u32x4 bu = *(const u32x4*)&bL[buf][ntl * 512 + lane * 8];
                acc[ntl] = __builtin_amdgcn_mfma_f32_16x16x32_bf16(
                    afr, __builtin_bit_cast(bf16x8, bu), acc[ntl], 0, 0, 0);
            }
        }

        if (hasNext) {
            *(u32x4*)&aL[nbuf][m][kc * 8] = pack_bf16x8(av);
#pragma unroll
            for (int q = 0; q < 2; ++q) {
                const int ntl = wave + q * 4;
                if (ntl < NTLOC) *(u32x4*)&bL[nbuf][ntl * 512 + lane * 8] = bv[q];
            }
        }
        __syncthreads();
    }

    const int oc_l = lane & 15;
    const int mrow = wave * 16 + ((lane >> 4) << 2);
#pragma unroll
    for (int ntl = 0; ntl < 5; ++ntl) {
        if (ntl < NTLOC) {
            const int oc = (ntBase + ntl) * 16 + oc_l;
            const float bias = ob[oc];
            __hip_bfloat16* op = offw + ((size_t)b * 144 + oc) * CH_HW + hrow * 64 + mrow;
#pragma unroll
            for (int r = 0; r < 4; ++r)
                op[r] = __float2bfloat16(acc[ntl][r] + bias);
        }
    }
}

// ---------------------------------------------------------------------------
// Kernel 2: fused bilinear sampling + grouped-conv MFMA GEMM.
// Per (b,g): M=4096 px, N=32 oc, K=288 (tap-major: K-step = 32 ch of 1 tap).
// Wave = 32 px (2 M-tiles) x 2 N-tiles; A-frag built in registers, no LDS.
// ---------------------------------------------------------------------------
struct Samp { int iA, iB, iC, iD; float wA, wB, wC, wD; };

__device__ __forceinline__ Samp make_samp(float py, float px) {
    const float y0f = floorf(py), x0f = floorf(px);
    const int iy0 = (int)y0f, ix0 = (int)x0f;
    const int iy1 = iy0 + 1,  ix1 = ix0 + 1;
    const float fy1 = py - y0f, fx1 = px - x0f;
    const float fy0 = 1.f - fy1, fx0 = 1.f - fx1;
    const bool vy0 = (iy0 >= 0) & (iy0 < 64);
    const bool vy1 = (iy1 >= 0) & (iy1 < 64);
    const bool vx0 = (ix0 >= 0) & (ix0 < 64);
    const bool vx1 = (ix1 >= 0) & (ix1 < 64);
    const int cy0 = min(max(iy0, 0), 63), cy1 = min(max(iy1, 0), 63);
    const int cx0 = min(max(ix0, 0), 63), cx1 = min(max(ix1, 0), 63);
    Samp s;
    s.iA = (cy0 << 6) + cx0; s.iB = (cy0 << 6) + cx1;
    s.iC = (cy1 << 6) + cx0; s.iD = (cy1 << 6) + cx1;
    s.wA = (vy0 & vx0) ? fy0 * fx0 : 0.f;
    s.wB = (vy0 & vx1) ? fy0 * fx1 : 0.f;
    s.wC = (vy1 & vx0) ? fy1 * fx0 : 0.f;
    s.wD = (vy1 & vx1) ? fy1 * fx1 : 0.f;
    return s;
}

__global__ __launch_bounds__(256) void deform3(const float* __restrict__ x,
                                               const __hip_bfloat16* __restrict__ offw,
                                               const __hip_bfloat16* __restrict__ dwb,
                                               const float* __restrict__ db,
                                               float* __restrict__ out)
{
    const int pt = blockIdx.x;     // 0..31 (128 px per block)
    const int g  = blockIdx.y;
    const int b  = blockIdx.z;
    const int tid  = threadIdx.x;
    const int lane = tid & 63, wave = tid >> 6;
    const int pixbase = (pt << 7) + (wave << 5);   // wave's 32 pixels
    const int arow = lane & 15;                    // pixel within M-tile
    const int cgrp = lane >> 4;                    // channel group (8 ch)

    const float* xg = x + ((size_t)b * 256 + g * 32 + cgrp * 8) * CH_HW;
    const __hip_bfloat16* offp = offw + ((size_t)b * 144 + g * 18) * CH_HW;
    const __hip_bfloat16* wgb = dwb + (size_t)g * 9 * 2 * 512;

    f32x4 acc[2][2];
#pragma unroll
    for (int mt = 0; mt < 2; ++mt)
#pragma unroll
        for (int nt = 0; nt < 2; ++nt) acc[mt][nt] = (f32x4){0.f, 0.f, 0.f, 0.f};

#pragma unroll 1
    for (int k = 0; k < 9; ++k) {
        const u32x4 bu0 = *(const u32x4*)(wgb + (size_t)(k * 2 + 0) * 512 + lane * 8);
        const u32x4 bu1 = *(const u32x4*)(wgb + (size_t)(k * 2 + 1) * 512 + lane * 8);
        const bf16x8 bf0 = __builtin_bit_cast(bf16x8, bu0);
        const bf16x8 bf1 = __builtin_bit_cast(bf16x8, bu1);
        const int ki = k / 3, kj = k % 3;

#pragma unroll
        for (int mt = 0; mt < 2; ++mt) {
            const int pix = pixbase + mt * 16 + arow;
            const int h = pix >> 6, w = pix & 63;
            const float oy = __bfloat162float(offp[(2 * k) * CH_HW + pix]);
            const float ox = __bfloat162float(offp[(2 * k + 1) * CH_HW + pix]);
            const Samp s = make_samp((float)(h - 1 + ki) + oy,
                                     (float)(w - 1 + kj) + ox);
            float v[8];
#pragma unroll
            for (int j = 0; j < 8; ++j) {
                const float* xc = xg + (size_t)j * CH_HW;
                v[j] = s.wA * xc[s.iA] + s.wB * xc[s.iB] +
                       s.wC * xc[s.iC] + s.wD * xc[s.iD];
            }
            const u32x4 au = pack_bf16x8(v);
            const bf16x8 afr = __builtin_bit_cast(bf16x8, au);
            acc[mt][0] = __builtin_amdgcn_mfma_f32_16x16x32_bf16(afr, bf0, acc[mt][0], 0, 0, 0);
            acc[mt][1] = __builtin_amdgcn_mfma_f32_16x16x32_bf16(afr, bf1, acc[mt][1], 0, 0, 0);
        }
    }

    // C layout: col(oc)=lane&15, row(px)=(lane>>4)*4+r -> float4 store per frag
    const int ocl = lane & 15;
#pragma unroll
    for (int mt = 0; mt < 2; ++mt)
#pragma unroll
        for (int nt = 0; nt < 2; ++nt) {
            const int oc = g * 32 + nt * 16 + ocl;
            const float bias = db[oc];
            const int pix = pixbase + mt * 16 + ((lane >> 4) << 2);
            float4 o4;
            o4.x = acc[mt][nt][0] + bias;
            o4.y = acc[mt][nt][1] + bias;
            o4.z = acc[mt][nt][2] + bias;
            o4.w = acc[mt][nt][3] + bias;
            *(float4*)&out[((size_t)b * 256 + oc) * CH_HW + pix] = o4;
        }
}

// ---------------------------------------------------------------------------
extern "C" void kernel_launch(void* const* d_in, const int* in_sizes, int n_in,
                              void* d_out, int out_size, void* d_ws, size_t ws_size,
                              hipStream_t stream) {
    const float* x  = (const float*)d_in[0];
    const float* ow = (const float*)d_in[1];
    const float* ob = (const float*)d_in[2];
    const float* dw = (const float*)d_in[3];
    const float* db = (const float*)d_in[4];
    float* out = (float*)d_out;

    __hip_bfloat16* wf   = (__hip_bfloat16*)d_ws;
    __hip_bfloat16* offw = (__hip_bfloat16*)((char*)d_ws + WF_BYTES);
    __hip_bfloat16* dwb  = (__hip_bfloat16*)((char*)d_ws + WF_BYTES + OFFW_BYTES);

    repack_w<<<(WF_ELEMS + 255) / 256, 256, 0, stream>>>(ow, wf);
    repack_dwb<<<(DWB_ELEMS + 255) / 256, 256, 0, stream>>>(dw, dwb);
    offs_mfma<<<512, 256, 0, stream>>>(x, wf, ob, offw);
    deform3<<<dim3(32, 8, 4), 256, 0, stream>>>(x, offw, dwb, db, out);
}

// Round 5
// 116.096 us; speedup vs baseline: 2.1739x; 1.3821x over previous
//
#include <hip/hip_runtime.h>
#include <hip/hip_bf16.h>
#include <cstddef>
#include <cstdint>

#define CH_HW 4096   // 64*64

typedef __bf16  bf16x8  __attribute__((ext_vector_type(8)));
typedef float   f32x4   __attribute__((ext_vector_type(4)));
typedef unsigned int u32x4 __attribute__((ext_vector_type(4)));

// d_ws layout (fast path):
//   [0, WF)            bf16 offset-conv weight B-frags
//   [WF, +OFFW)        bf16 offset field
//   [WF+OFFW, +DWB)    bf16 deform weight B-frags
//   [WF+OFFW+DWB,+XT)  bf16 pixel-major x: xt[b][g][pix][c32]
#define WF_ELEMS 331776                 // 72 ks * 9 nt * 64 lane * 8
#define WF_BYTES (WF_ELEMS * 2)
#define OFFW_BYTES (4u * 144u * CH_HW * 2u)   // 4,718,592
#define DWB_ELEMS (8 * 9 * 2 * 512)
#define DWB_BYTES (DWB_ELEMS * 2)
#define XT_BYTES ((size_t)4 * 8 * CH_HW * 32 * 2)   // 8,388,608

__device__ __forceinline__ u32x4 pack_bf16x8(const float av[8]) {
    u32x4 ad;
#pragma unroll
    for (int jj = 0; jj < 4; ++jj) {
        const unsigned int lo = __builtin_bit_cast(unsigned short, __float2bfloat16(av[2 * jj]));
        const unsigned int hi = __builtin_bit_cast(unsigned short, __float2bfloat16(av[2 * jj + 1]));
        ad[jj] = lo | (hi << 16);
    }
    return ad;
}
__device__ __forceinline__ float bf16lo(unsigned int u) {
    return __builtin_bit_cast(float, u << 16);
}
__device__ __forceinline__ float bf16hi(unsigned int u) {
    return __builtin_bit_cast(float, u & 0xFFFF0000u);
}

// ---------------------------------------------------------------------------
// Kernel 0a: repack offset_w -> MFMA B-fragment stream bf16
// ---------------------------------------------------------------------------
__global__ __launch_bounds__(256) void repack_w(const float* __restrict__ ow,
                                                __hip_bfloat16* __restrict__ wf)
{
    const int t = blockIdx.x * 256 + threadIdx.x;
    if (t >= WF_ELEMS) return;
    const int j    = t & 7;
    const int lane = (t >> 3) & 63;
    const int tmp  = t >> 9;
    const int nt   = tmp % 9;
    const int ks   = tmp / 9;
    const int tap  = ks >> 3, icb = ks & 7;
    const int oc   = nt * 16 + (lane & 15);
    const int ic   = icb * 32 + (lane >> 4) * 8 + j;
    wf[t] = __float2bfloat16(ow[(size_t)oc * 2304 + ic * 9 + tap]);
}

// ---------------------------------------------------------------------------
// Kernel 0b: repack deform_w -> B-frag stream bf16
// ---------------------------------------------------------------------------
__global__ __launch_bounds__(256) void repack_dwb(const float* __restrict__ dw,
                                                  __hip_bfloat16* __restrict__ dwb)
{
    const int t = blockIdx.x * 256 + threadIdx.x;
    if (t >= DWB_ELEMS) return;
    const int j    = t & 7;
    const int lane = (t >> 3) & 63;
    const int nt   = (t >> 9) & 1;
    const int gk   = t >> 10;
    const int k    = gk % 9;
    const int g    = gk / 9;
    const int oc   = g * 32 + nt * 16 + (lane & 15);
    const int c    = (lane >> 4) * 8 + j;
    dwb[t] = __float2bfloat16(dw[(size_t)oc * 288 + c * 9 + k]);
}

// ---------------------------------------------------------------------------
// Kernel 0c: transpose x (b,c,h,w) f32 -> xt[b][g][pix][c32] bf16
// ---------------------------------------------------------------------------
__global__ __launch_bounds__(256) void xt_pack(const float* __restrict__ x,
                                               __hip_bfloat16* __restrict__ xt)
{
    const int chunk = blockIdx.x;   // 0..15
    const int g = blockIdx.y, b = blockIdx.z;
    const int pix = (chunk << 8) + threadIdx.x;
    const float* xs = x + ((size_t)b * 256 + g * 32) * CH_HW + pix;
    __hip_bfloat16* xp = xt + (((size_t)b * 8 + g) * CH_HW + pix) * 32;
#pragma unroll
    for (int q = 0; q < 4; ++q) {
        float av[8];
#pragma unroll
        for (int j = 0; j < 8; ++j) av[j] = xs[(size_t)(q * 8 + j) * CH_HW];
        *(u32x4*)(xp + q * 8) = pack_bf16x8(av);
    }
}

// ---------------------------------------------------------------------------
// Kernel 1 (fast): offset conv, register-direct MFMA GEMM from xt. No LDS.
// block = (hrow, nt, b); wave = 16-px M-tile of the row; 1 MFMA per K-step.
// ---------------------------------------------------------------------------
__global__ __launch_bounds__(256, 8) void offs_mfma2(
    const __hip_bfloat16* __restrict__ xt,
    const __hip_bfloat16* __restrict__ wf,
    const float* __restrict__ ob,
    __hip_bfloat16* __restrict__ offw)
{
    const int hrow = blockIdx.x;       // 0..63
    const int nt   = blockIdx.y;       // 0..8
    const int b    = blockIdx.z;
    const int tid  = threadIdx.x;
    const int lane = tid & 63, wave = tid >> 6;
    const int arow = lane & 15, cgrp = lane >> 4;
    const int col  = wave * 16 + arow;   // output pixel column

    const __hip_bfloat16* xb = xt + (size_t)b * 8 * CH_HW * 32;

    auto loadA = [&](int ks) -> u32x4 {
        const int tap = ks >> 3, icb = ks & 7;
        const int dy = tap / 3 - 1, dx = tap % 3 - 1;
        const int sh = hrow + dy, sw = col + dx;
        const bool valid = (sh >= 0) & (sh < 64) & (sw >= 0) & (sw < 64);
        const int spix = (min(max(sh, 0), 63) << 6) + min(max(sw, 0), 63);
        u32x4 a = *(const u32x4*)(xb + ((size_t)icb * CH_HW + spix) * 32 + cgrp * 8);
        if (!valid) a = (u32x4){0, 0, 0, 0};
        return a;
    };
    auto loadB = [&](int ks) -> u32x4 {
        return *(const u32x4*)(wf + ((size_t)(ks * 9 + nt) * 64 + lane) * 8);
    };

    f32x4 acc = (f32x4){0.f, 0.f, 0.f, 0.f};
    u32x4 a0 = loadA(0), b0 = loadB(0);
#pragma unroll 1
    for (int ks = 0; ks < 71; ++ks) {
        const u32x4 a1 = loadA(ks + 1);
        const u32x4 b1 = loadB(ks + 1);
        acc = __builtin_amdgcn_mfma_f32_16x16x32_bf16(
            __builtin_bit_cast(bf16x8, a0), __builtin_bit_cast(bf16x8, b0), acc, 0, 0, 0);
        a0 = a1; b0 = b1;
    }
    acc = __builtin_amdgcn_mfma_f32_16x16x32_bf16(
        __builtin_bit_cast(bf16x8, a0), __builtin_bit_cast(bf16x8, b0), acc, 0, 0, 0);

    // C: col(oc)=lane&15, row(px)=cgrp*4+r
    const int oc = nt * 16 + arow;
    const float bias = ob[oc];
    float av[4];
#pragma unroll
    for (int r = 0; r < 4; ++r) av[r] = acc[r] + bias;
    unsigned int p0 = (unsigned int)__builtin_bit_cast(unsigned short, __float2bfloat16(av[0])) |
                      ((unsigned int)__builtin_bit_cast(unsigned short, __float2bfloat16(av[1])) << 16);
    unsigned int p1 = (unsigned int)__builtin_bit_cast(unsigned short, __float2bfloat16(av[2])) |
                      ((unsigned int)__builtin_bit_cast(unsigned short, __float2bfloat16(av[3])) << 16);
    const int pxb = hrow * 64 + wave * 16 + (cgrp << 2);
    unsigned int* op = (unsigned int*)(offw + ((size_t)b * 144 + oc) * CH_HW + pxb);
    op[0] = p0; op[1] = p1;
}

// ---------------------------------------------------------------------------
// Kernel 2 (fast): bilinear sampling from xt + grouped-conv MFMA. No LDS.
// block = 64 px of (b,g); wave = 16-px M-tile x 2 N-tiles.
// ---------------------------------------------------------------------------
struct Samp { int iA, iB, iC, iD; float wA, wB, wC, wD; };

__device__ __forceinline__ Samp make_samp(float py, float px) {
    const float y0f = floorf(py), x0f = floorf(px);
    const int iy0 = (int)y0f, ix0 = (int)x0f;
    const int iy1 = iy0 + 1,  ix1 = ix0 + 1;
    const float fy1 = py - y0f, fx1 = px - x0f;
    const float fy0 = 1.f - fy1, fx0 = 1.f - fx1;
    const bool vy0 = (iy0 >= 0) & (iy0 < 64);
    const bool vy1 = (iy1 >= 0) & (iy1 < 64);
    const bool vx0 = (ix0 >= 0) & (ix0 < 64);
    const bool vx1 = (ix1 >= 0) & (ix1 < 64);
    const int cy0 = min(max(iy0, 0), 63), cy1 = min(max(iy1, 0), 63);
    const int cx0 = min(max(ix0, 0), 63), cx1 = min(max(ix1, 0), 63);
    Samp s;
    s.iA = (cy0 << 6) + cx0; s.iB = (cy0 << 6) + cx1;
    s.iC = (cy1 << 6) + cx0; s.iD = (cy1 << 6) + cx1;
    s.wA = (vy0 & vx0) ? fy0 * fx0 : 0.f;
    s.wB = (vy0 & vx1) ? fy0 * fx1 : 0.f;
    s.wC = (vy1 & vx0) ? fy1 * fx0 : 0.f;
    s.wD = (vy1 & vx1) ? fy1 * fx1 : 0.f;
    return s;
}

__global__ __launch_bounds__(256, 6) void deform4(
    const __hip_bfloat16* __restrict__ xt,
    const __hip_bfloat16* __restrict__ offw,
    const __hip_bfloat16* __restrict__ dwb,
    const float* __restrict__ db,
    float* __restrict__ out)
{
    const int pt = blockIdx.x;  // 0..63 (64 px per block)
    const int g  = blockIdx.y;
    const int b  = blockIdx.z;
    const int tid = threadIdx.x;
    const int lane = tid & 63, wave = tid >> 6;
    const int arow = lane & 15, cgrp = lane >> 4;
    const int px = (pt << 6) + (wave << 4) + arow;
    const int h = px >> 6, w = px & 63;

    const __hip_bfloat16* xg   = xt + ((size_t)b * 8 + g) * CH_HW * 32;
    const __hip_bfloat16* offp = offw + ((size_t)b * 144 + g * 18) * CH_HW + px;
    const __hip_bfloat16* wgb  = dwb + (size_t)g * 9 * 2 * 512 + lane * 8;

    // hoist all 18 offsets out of the dependent chain
    float offy[9], offx[9];
#pragma unroll
    for (int k = 0; k < 9; ++k) {
        offy[k] = __bfloat162float(offp[(size_t)(2 * k) * CH_HW]);
        offx[k] = __bfloat162float(offp[(size_t)(2 * k + 1) * CH_HW]);
    }

    f32x4 acc0 = (f32x4){0.f, 0.f, 0.f, 0.f};
    f32x4 acc1 = (f32x4){0.f, 0.f, 0.f, 0.f};

#pragma unroll 1
    for (int k = 0; k < 9; ++k) {
        const Samp s = make_samp((float)(h - 1 + k / 3) + offy[k],
                                 (float)(w - 1 + k % 3) + offx[k]);
        const u32x4 cA = *(const u32x4*)(xg + (size_t)s.iA * 32 + cgrp * 8);
        const u32x4 cB = *(const u32x4*)(xg + (size_t)s.iB * 32 + cgrp * 8);
        const u32x4 cC = *(const u32x4*)(xg + (size_t)s.iC * 32 + cgrp * 8);
        const u32x4 cD = *(const u32x4*)(xg + (size_t)s.iD * 32 + cgrp * 8);
        const u32x4 bu0 = *(const u32x4*)(wgb + (size_t)(k * 2 + 0) * 512);
        const u32x4 bu1 = *(const u32x4*)(wgb + (size_t)(k * 2 + 1) * 512);

        float v[8];
#pragma unroll
        for (int q = 0; q < 4; ++q) {
            v[2 * q] = s.wA * bf16lo(cA[q]) + s.wB * bf16lo(cB[q]) +
                       s.wC * bf16lo(cC[q]) + s.wD * bf16lo(cD[q]);
            v[2 * q + 1] = s.wA * bf16hi(cA[q]) + s.wB * bf16hi(cB[q]) +
                           s.wC * bf16hi(cC[q]) + s.wD * bf16hi(cD[q]);
        }
        const bf16x8 afr = __builtin_bit_cast(bf16x8, pack_bf16x8(v));
        acc0 = __builtin_amdgcn_mfma_f32_16x16x32_bf16(
            afr, __builtin_bit_cast(bf16x8, bu0), acc0, 0, 0, 0);
        acc1 = __builtin_amdgcn_mfma_f32_16x16x32_bf16(
            afr, __builtin_bit_cast(bf16x8, bu1), acc1, 0, 0, 0);
    }

    const int pix4 = (pt << 6) + (wave << 4) + (cgrp << 2);
#pragma unroll
    for (int nt = 0; nt < 2; ++nt) {
        const f32x4 a = nt ? acc1 : acc0;
        const int oc = g * 32 + nt * 16 + arow;
        const float bias = db[oc];
        float4 o4;
        o4.x = a[0] + bias; o4.y = a[1] + bias;
        o4.z = a[2] + bias; o4.w = a[3] + bias;
        *(float4*)&out[((size_t)b * 256 + oc) * CH_HW + pix4] = o4;
    }
}

// ===========================================================================
// Fallback path (round-4 proven, needs only 5.5 MB ws): offs_mfma + deform3
// ===========================================================================
__device__ __forceinline__ void stageA_load(const float* __restrict__ xb,
                                            int hrow, int m, int kc, int ks,
                                            float av[8])
{
    const int tap = ks >> 3, icb = ks & 7;
    const int dy = tap / 3 - 1, dx = tap % 3 - 1;
    const int sh = hrow + dy, sw = m + dx;
    const float msk = (sh >= 0 && sh < 64 && sw >= 0 && sw < 64) ? 1.f : 0.f;
    const int shc = min(max(sh, 0), 63), swc = min(max(sw, 0), 63);
    const float* p = xb + (size_t)(icb * 32 + kc * 8) * CH_HW + (shc << 6) + swc;
#pragma unroll
    for (int j = 0; j < 8; ++j) av[j] = p[(size_t)j * CH_HW] * msk;
}

__global__ __launch_bounds__(256) void offs_mfma(const float* __restrict__ x,
                                                 const __hip_bfloat16* __restrict__ wf,
                                                 const float* __restrict__ ob,
                                                 __hip_bfloat16* __restrict__ offw)
{
    __shared__ __align__(16) unsigned short aL[2][64][40];
    __shared__ __align__(16) unsigned short bL[2][2560];

    const int bid  = blockIdx.x;
    const int nh   = bid & 1;
    const int hrow = (bid >> 1) & 63;
    const int b    = bid >> 7;
    const int ntBase = nh * 5;
    const int NTLOC  = 5 - nh;
    const int tid  = threadIdx.x;
    const int lane = tid & 63, wave = tid >> 6;
    const int m    = lane;
    const int kc   = wave;

    const float* xb = x + (size_t)b * 256 * CH_HW;

    f32x4 acc[5];
#pragma unroll
    for (int q = 0; q < 5; ++q) acc[q] = (f32x4){0.f, 0.f, 0.f, 0.f};

    {
        float av[8]; u32x4 bv[2];
        stageA_load(xb, hrow, m, kc, 0, av);
#pragma unroll
        for (int q = 0; q < 2; ++q) {
            const int ntl = wave + q * 4;
            if (ntl < NTLOC)
                bv[q] = *(const u32x4*)(wf + ((size_t)(ntBase + ntl) * 64 + lane) * 8);
        }
        *(u32x4*)&aL[0][m][kc * 8] = pack_bf16x8(av);
#pragma unroll
        for (int q = 0; q < 2; ++q) {
            const int ntl = wave + q * 4;
            if (ntl < NTLOC) *(u32x4*)&bL[0][ntl * 512 + lane * 8] = bv[q];
        }
    }
    __syncthreads();

    for (int ks = 0; ks < 72; ++ks) {
        const int buf = ks & 1, nbuf = buf ^ 1;
        const bool hasNext = (ks + 1) < 72;

        float av[8]; u32x4 bv[2];
        if (hasNext) {
            stageA_load(xb, hrow, m, kc, ks + 1, av);
#pragma unroll
            for (int q = 0; q < 2; ++q) {
                const int ntl = wave + q * 4;
                if (ntl < NTLOC)
                    bv[q] = *(const u32x4*)(wf + ((size_t)((ks + 1) * 9 + ntBase + ntl) * 64 + lane) * 8);
            }
        }

        const u32x4 au = *(const u32x4*)&aL[buf][wave * 16 + (lane & 15)][(lane >> 4) * 8];
        const bf16x8 afr = __builtin_bit_cast(bf16x8, au);
#pragma unroll
        for (int ntl = 0; ntl < 5; ++ntl) {
            if (ntl < NTLOC) {
                const u32x4 bu = *(const u32x4*)&bL[buf][ntl * 512 + lane * 8];
                acc[ntl] = __builtin_amdgcn_mfma_f32_16x16x32_bf16(
                    afr, __builtin_bit_cast(bf16x8, bu), acc[ntl], 0, 0, 0);
            }
        }

        if (hasNext) {
            *(u32x4*)&aL[nbuf][m][kc * 8] = pack_bf16x8(av);
#pragma unroll
            for (int q = 0; q < 2; ++q) {
                const int ntl = wave + q * 4;
                if (ntl < NTLOC) *(u32x4*)&bL[nbuf][ntl * 512 + lane * 8] = bv[q];
            }
        }
        __syncthreads();
    }

    const int oc_l = lane & 15;
    const int mrow = wave * 16 + ((lane >> 4) << 2);
#pragma unroll
    for (int ntl = 0; ntl < 5; ++ntl) {
        if (ntl < NTLOC) {
            const int oc = (ntBase + ntl) * 16 + oc_l;
            const float bias = ob[oc];
            __hip_bfloat16* op = offw + ((size_t)b * 144 + oc) * CH_HW + hrow * 64 + mrow;
#pragma unroll
            for (int r = 0; r < 4; ++r)
                op[r] = __float2bfloat16(acc[ntl][r] + bias);
        }
    }
}

__global__ __launch_bounds__(256) void deform3(const float* __restrict__ x,
                                               const __hip_bfloat16* __restrict__ offw,
                                               const __hip_bfloat16* __restrict__ dwb,
                                               const float* __restrict__ db,
                                               float* __restrict__ out)
{
    const int pt = blockIdx.x;
    const int g  = blockIdx.y;
    const int b  = blockIdx.z;
    const int tid  = threadIdx.x;
    const int lane = tid & 63, wave = tid >> 6;
    const int pixbase = (pt << 7) + (wave << 5);
    const int arow = lane & 15;
    const int cgrp = lane >> 4;

    const float* xg = x + ((size_t)b * 256 + g * 32 + cgrp * 8) * CH_HW;
    const __hip_bfloat16* offp = offw + ((size_t)b * 144 + g * 18) * CH_HW;
    const __hip_bfloat16* wgb = dwb + (size_t)g * 9 * 2 * 512;

    f32x4 acc[2][2];
#pragma unroll
    for (int mt = 0; mt < 2; ++mt)
#pragma unroll
        for (int nt = 0; nt < 2; ++nt) acc[mt][nt] = (f32x4){0.f, 0.f, 0.f, 0.f};

#pragma unroll 1
    for (int k = 0; k < 9; ++k) {
        const u32x4 bu0 = *(const u32x4*)(wgb + (size_t)(k * 2 + 0) * 512 + lane * 8);
        const u32x4 bu1 = *(const u32x4*)(wgb + (size_t)(k * 2 + 1) * 512 + lane * 8);
        const bf16x8 bf0 = __builtin_bit_cast(bf16x8, bu0);
        const bf16x8 bf1 = __builtin_bit_cast(bf16x8, bu1);
        const int ki = k / 3, kj = k % 3;

#pragma unroll
        for (int mt = 0; mt < 2; ++mt) {
            const int pix = pixbase + mt * 16 + arow;
            const int h = pix >> 6, w = pix & 63;
            const float oy = __bfloat162float(offp[(2 * k) * CH_HW + pix]);
            const float ox = __bfloat162float(offp[(2 * k + 1) * CH_HW + pix]);
            const Samp s = make_samp((float)(h - 1 + ki) + oy,
                                     (float)(w - 1 + kj) + ox);
            float v[8];
#pragma unroll
            for (int j = 0; j < 8; ++j) {
                const float* xc = xg + (size_t)j * CH_HW;
                v[j] = s.wA * xc[s.iA] + s.wB * xc[s.iB] +
                       s.wC * xc[s.iC] + s.wD * xc[s.iD];
            }
            const bf16x8 afr = __builtin_bit_cast(bf16x8, pack_bf16x8(v));
            acc[mt][0] = __builtin_amdgcn_mfma_f32_16x16x32_bf16(afr, bf0, acc[mt][0], 0, 0, 0);
            acc[mt][1] = __builtin_amdgcn_mfma_f32_16x16x32_bf16(afr, bf1, acc[mt][1], 0, 0, 0);
        }
    }

    const int ocl = lane & 15;
#pragma unroll
    for (int mt = 0; mt < 2; ++mt)
#pragma unroll
        for (int nt = 0; nt < 2; ++nt) {
            const int oc = g * 32 + nt * 16 + ocl;
            const float bias = db[oc];
            const int pix = pixbase + mt * 16 + ((lane >> 4) << 2);
            float4 o4;
            o4.x = acc[mt][nt][0] + bias;
            o4.y = acc[mt][nt][1] + bias;
            o4.z = acc[mt][nt][2] + bias;
            o4.w = acc[mt][nt][3] + bias;
            *(float4*)&out[((size_t)b * 256 + oc) * CH_HW + pix] = o4;
        }
}

// ---------------------------------------------------------------------------
extern "C" void kernel_launch(void* const* d_in, const int* in_sizes, int n_in,
                              void* d_out, int out_size, void* d_ws, size_t ws_size,
                              hipStream_t stream) {
    const float* x  = (const float*)d_in[0];
    const float* ow = (const float*)d_in[1];
    const float* ob = (const float*)d_in[2];
    const float* dw = (const float*)d_in[3];
    const float* db = (const float*)d_in[4];
    float* out = (float*)d_out;

    __hip_bfloat16* wf   = (__hip_bfloat16*)d_ws;
    __hip_bfloat16* offw = (__hip_bfloat16*)((char*)d_ws + WF_BYTES);
    __hip_bfloat16* dwb  = (__hip_bfloat16*)((char*)d_ws + WF_BYTES + OFFW_BYTES);
    __hip_bfloat16* xt   = (__hip_bfloat16*)((char*)d_ws + WF_BYTES + OFFW_BYTES + DWB_BYTES);

    const size_t needed = (size_t)WF_BYTES + OFFW_BYTES + DWB_BYTES + XT_BYTES;

    repack_w<<<(WF_ELEMS + 255) / 256, 256, 0, stream>>>(ow, wf);
    repack_dwb<<<(DWB_ELEMS + 255) / 256, 256, 0, stream>>>(dw, dwb);

    if (ws_size >= needed) {
        xt_pack<<<dim3(16, 8, 4), 256, 0, stream>>>(x, xt);
        offs_mfma2<<<dim3(64, 9, 4), 256, 0, stream>>>(xt, wf, ob, offw);
        deform4<<<dim3(64, 8, 4), 256, 0, stream>>>(xt, offw, dwb, db, out);
    } else {
        offs_mfma<<<512, 256, 0, stream>>>(x, wf, ob, offw);
        deform3<<<dim3(32, 8, 4), 256, 0, stream>>>(x, offw, dwb, db, out);
    }
}

// Round 6
// 84.720 us; speedup vs baseline: 2.9790x; 1.3703x over previous
//
#include <hip/hip_runtime.h>
#include <hip/hip_bf16.h>
#include <cstddef>
#include <cstdint>

#define CH_HW 4096   // 64*64

typedef __bf16  bf16x8  __attribute__((ext_vector_type(8)));
typedef float   f32x4   __attribute__((ext_vector_type(4)));
typedef unsigned int u32x4 __attribute__((ext_vector_type(4)));

// d_ws layout (fast path):
//   [0, WF)            bf16 offset-conv weight B-frags
//   [WF, +OFFW)        bf16 offset field
//   [WF+OFFW, +DWB)    bf16 deform weight B-frags
//   [WF+OFFW+DWB,+XT)  bf16 pixel-major x: xt[b][g][pix][c32]
#define WF_ELEMS 331776                 // 72 ks * 9 nt * 64 lane * 8
#define WF_BYTES (WF_ELEMS * 2)
#define OFFW_BYTES (4u * 144u * CH_HW * 2u)   // 4,718,592
#define DWB_ELEMS (8 * 9 * 2 * 512)
#define DWB_BYTES (DWB_ELEMS * 2)
#define XT_BYTES ((size_t)4 * 8 * CH_HW * 32 * 2)   // 8,388,608

__device__ __forceinline__ u32x4 pack_bf16x8(const float av[8]) {
    u32x4 ad;
#pragma unroll
    for (int jj = 0; jj < 4; ++jj) {
        const unsigned int lo = __builtin_bit_cast(unsigned short, __float2bfloat16(av[2 * jj]));
        const unsigned int hi = __builtin_bit_cast(unsigned short, __float2bfloat16(av[2 * jj + 1]));
        ad[jj] = lo | (hi << 16);
    }
    return ad;
}
__device__ __forceinline__ float bf16lo(unsigned int u) {
    return __builtin_bit_cast(float, u << 16);
}
__device__ __forceinline__ float bf16hi(unsigned int u) {
    return __builtin_bit_cast(float, u & 0xFFFF0000u);
}

// ---------------------------------------------------------------------------
// Kernel 0a: repack offset_w -> MFMA B-fragment stream bf16
// Wf[ks][nt][lane][j]; ks=tap*8+icb; oc=nt*16+(lane&15); ic=icb*32+(lane>>4)*8+j
// ---------------------------------------------------------------------------
__global__ __launch_bounds__(256) void repack_w(const float* __restrict__ ow,
                                                __hip_bfloat16* __restrict__ wf)
{
    const int t = blockIdx.x * 256 + threadIdx.x;
    if (t >= WF_ELEMS) return;
    const int j    = t & 7;
    const int lane = (t >> 3) & 63;
    const int tmp  = t >> 9;
    const int nt   = tmp % 9;
    const int ks   = tmp / 9;
    const int tap  = ks >> 3, icb = ks & 7;
    const int oc   = nt * 16 + (lane & 15);
    const int ic   = icb * 32 + (lane >> 4) * 8 + j;
    wf[t] = __float2bfloat16(ow[(size_t)oc * 2304 + ic * 9 + tap]);
}

// ---------------------------------------------------------------------------
// Kernel 0b: repack deform_w -> B-frag stream bf16
// ---------------------------------------------------------------------------
__global__ __launch_bounds__(256) void repack_dwb(const float* __restrict__ dw,
                                                  __hip_bfloat16* __restrict__ dwb)
{
    const int t = blockIdx.x * 256 + threadIdx.x;
    if (t >= DWB_ELEMS) return;
    const int j    = t & 7;
    const int lane = (t >> 3) & 63;
    const int nt   = (t >> 9) & 1;
    const int gk   = t >> 10;
    const int k    = gk % 9;
    const int g    = gk / 9;
    const int oc   = g * 32 + nt * 16 + (lane & 15);
    const int c    = (lane >> 4) * 8 + j;
    dwb[t] = __float2bfloat16(dw[(size_t)oc * 288 + c * 9 + k]);
}

// ---------------------------------------------------------------------------
// Kernel 0c: transpose x (b,c,h,w) f32 -> xt[b][g][pix][c32] bf16
// ---------------------------------------------------------------------------
__global__ __launch_bounds__(256) void xt_pack(const float* __restrict__ x,
                                               __hip_bfloat16* __restrict__ xt)
{
    const int chunk = blockIdx.x;   // 0..15
    const int g = blockIdx.y, b = blockIdx.z;
    const int pix = (chunk << 8) + threadIdx.x;
    const float* xs = x + ((size_t)b * 256 + g * 32) * CH_HW + pix;
    __hip_bfloat16* xp = xt + (((size_t)b * 8 + g) * CH_HW + pix) * 32;
#pragma unroll
    for (int q = 0; q < 4; ++q) {
        float av[8];
#pragma unroll
        for (int j = 0; j < 8; ++j) av[j] = xs[(size_t)(q * 8 + j) * CH_HW];
        *(u32x4*)(xp + q * 8) = pack_bf16x8(av);
    }
}

// ---------------------------------------------------------------------------
// Kernel 1 (fast): offset conv MFMA. One WAVE = 16 px x ALL 144 oc (9 acc).
// Per K-step: 1 A-load + 9 B-loads + 9 MFMA. 2-slot pipeline. No LDS.
// 1024 single-wave blocks, XCD-swizzled so each b's xt slice is L2-local.
// ---------------------------------------------------------------------------
__global__ __launch_bounds__(64) void offs_mfma3(
    const __hip_bfloat16* __restrict__ xt,
    const __hip_bfloat16* __restrict__ wf,
    const float* __restrict__ ob,
    __hip_bfloat16* __restrict__ offw)
{
    const int bid  = blockIdx.x;          // 0..1023
    const int xcd  = bid & 7;
    const int q    = bid >> 3;            // 0..127
    const int b    = xcd >> 1;            // 2 XCDs per batch image
    const int flat = q * 2 + (xcd & 1);   // 0..255
    const int hrow = flat >> 2;
    const int mt   = flat & 3;
    const int lane = threadIdx.x;
    const int arow = lane & 15, cgrp = lane >> 4;
    const int col  = mt * 16 + arow;      // pixel column in row hrow

    const __hip_bfloat16* xb  = xt + (size_t)b * 8 * CH_HW * 32;
    const __hip_bfloat16* wfl = wf + (size_t)lane * 8;

    auto loadA = [&](int ks) -> u32x4 {
        const int tap = ks >> 3, icb = ks & 7;
        const int dy = tap / 3 - 1, dx = tap % 3 - 1;
        const int sh = hrow + dy, sw = col + dx;
        const bool valid = (sh >= 0) & (sh < 64) & (sw >= 0) & (sw < 64);
        const int spix = (min(max(sh, 0), 63) << 6) + min(max(sw, 0), 63);
        u32x4 a = *(const u32x4*)(xb + ((size_t)icb * CH_HW + spix) * 32 + cgrp * 8);
        if (!valid) a = (u32x4){0, 0, 0, 0};
        return a;
    };

    f32x4 acc[9];
#pragma unroll
    for (int nt = 0; nt < 9; ++nt) acc[nt] = (f32x4){0.f, 0.f, 0.f, 0.f};

    // prologue: fill slot0 (ks=0) and slot1 (ks=1)
    u32x4 a0 = loadA(0), a1 = loadA(1);
    u32x4 b0[9], b1[9];
#pragma unroll
    for (int nt = 0; nt < 9; ++nt)
        b0[nt] = *(const u32x4*)(wfl + (size_t)(0 * 9 + nt) * 512);
#pragma unroll
    for (int nt = 0; nt < 9; ++nt)
        b1[nt] = *(const u32x4*)(wfl + (size_t)(1 * 9 + nt) * 512);

#pragma unroll 1
    for (int ks = 0; ks < 72; ks += 2) {
        // consume slot0 (ks)
        const bf16x8 af0 = __builtin_bit_cast(bf16x8, a0);
#pragma unroll
        for (int nt = 0; nt < 9; ++nt)
            acc[nt] = __builtin_amdgcn_mfma_f32_16x16x32_bf16(
                af0, __builtin_bit_cast(bf16x8, b0[nt]), acc[nt], 0, 0, 0);
        if (ks + 2 < 72) {
            a0 = loadA(ks + 2);
#pragma unroll
            for (int nt = 0; nt < 9; ++nt)
                b0[nt] = *(const u32x4*)(wfl + (size_t)((ks + 2) * 9 + nt) * 512);
        }
        // consume slot1 (ks+1)
        const bf16x8 af1 = __builtin_bit_cast(bf16x8, a1);
#pragma unroll
        for (int nt = 0; nt < 9; ++nt)
            acc[nt] = __builtin_amdgcn_mfma_f32_16x16x32_bf16(
                af1, __builtin_bit_cast(bf16x8, b1[nt]), acc[nt], 0, 0, 0);
        if (ks + 3 < 72) {
            a1 = loadA(ks + 3);
#pragma unroll
            for (int nt = 0; nt < 9; ++nt)
                b1[nt] = *(const u32x4*)(wfl + (size_t)((ks + 3) * 9 + nt) * 512);
        }
    }

    // epilogue: C: col(oc)=lane&15, row(px)=cgrp*4+r  (proven in offs_mfma2)
    const int pxb = hrow * 64 + mt * 16 + (cgrp << 2);
#pragma unroll
    for (int nt = 0; nt < 9; ++nt) {
        const int oc = nt * 16 + arow;
        const float bias = ob[oc];
        float av[4];
#pragma unroll
        for (int r = 0; r < 4; ++r) av[r] = acc[nt][r] + bias;
        unsigned int p0 = (unsigned int)__builtin_bit_cast(unsigned short, __float2bfloat16(av[0])) |
                          ((unsigned int)__builtin_bit_cast(unsigned short, __float2bfloat16(av[1])) << 16);
        unsigned int p1 = (unsigned int)__builtin_bit_cast(unsigned short, __float2bfloat16(av[2])) |
                          ((unsigned int)__builtin_bit_cast(unsigned short, __float2bfloat16(av[3])) << 16);
        unsigned int* op = (unsigned int*)(offw + ((size_t)b * 144 + oc) * CH_HW + pxb);
        op[0] = p0; op[1] = p1;
    }
}

// ---------------------------------------------------------------------------
// Kernel 2 (fast): bilinear sampling from xt + grouped-conv MFMA. No LDS.
// k-loop FULLY unrolled (static indexing -> no scratch; compiler pipelines).
// ---------------------------------------------------------------------------
struct Samp { int iA, iB, iC, iD; float wA, wB, wC, wD; };

__device__ __forceinline__ Samp make_samp(float py, float px) {
    const float y0f = floorf(py), x0f = floorf(px);
    const int iy0 = (int)y0f, ix0 = (int)x0f;
    const int iy1 = iy0 + 1,  ix1 = ix0 + 1;
    const float fy1 = py - y0f, fx1 = px - x0f;
    const float fy0 = 1.f - fy1, fx0 = 1.f - fx1;
    const bool vy0 = (iy0 >= 0) & (iy0 < 64);
    const bool vy1 = (iy1 >= 0) & (iy1 < 64);
    const bool vx0 = (ix0 >= 0) & (ix0 < 64);
    const bool vx1 = (ix1 >= 0) & (ix1 < 64);
    const int cy0 = min(max(iy0, 0), 63), cy1 = min(max(iy1, 0), 63);
    const int cx0 = min(max(ix0, 0), 63), cx1 = min(max(ix1, 0), 63);
    Samp s;
    s.iA = (cy0 << 6) + cx0; s.iB = (cy0 << 6) + cx1;
    s.iC = (cy1 << 6) + cx0; s.iD = (cy1 << 6) + cx1;
    s.wA = (vy0 & vx0) ? fy0 * fx0 : 0.f;
    s.wB = (vy0 & vx1) ? fy0 * fx1 : 0.f;
    s.wC = (vy1 & vx0) ? fy1 * fx0 : 0.f;
    s.wD = (vy1 & vx1) ? fy1 * fx1 : 0.f;
    return s;
}

__global__ __launch_bounds__(256, 4) void deform5(
    const __hip_bfloat16* __restrict__ xt,
    const __hip_bfloat16* __restrict__ offw,
    const __hip_bfloat16* __restrict__ dwb,
    const float* __restrict__ db,
    float* __restrict__ out)
{
    const int pt = blockIdx.x;  // 0..63 (64 px per block)
    const int g  = blockIdx.y;
    const int b  = blockIdx.z;
    const int tid = threadIdx.x;
    const int lane = tid & 63, wave = tid >> 6;
    const int arow = lane & 15, cgrp = lane >> 4;
    const int px = (pt << 6) + (wave << 4) + arow;
    const int h = px >> 6, w = px & 63;

    const __hip_bfloat16* xg   = xt + ((size_t)b * 8 + g) * CH_HW * 32;
    const __hip_bfloat16* offp = offw + ((size_t)b * 144 + g * 18) * CH_HW + px;
    const __hip_bfloat16* wgb  = dwb + (size_t)g * 9 * 2 * 512 + lane * 8;

    f32x4 acc0 = (f32x4){0.f, 0.f, 0.f, 0.f};
    f32x4 acc1 = (f32x4){0.f, 0.f, 0.f, 0.f};

#pragma unroll
    for (int k = 0; k < 9; ++k) {
        const float oy = __bfloat162float(offp[(size_t)(2 * k) * CH_HW]);
        const float ox = __bfloat162float(offp[(size_t)(2 * k + 1) * CH_HW]);
        const Samp s = make_samp((float)(h - 1 + k / 3) + oy,
                                 (float)(w - 1 + k % 3) + ox);
        const u32x4 cA = *(const u32x4*)(xg + (size_t)s.iA * 32 + cgrp * 8);
        const u32x4 cB = *(const u32x4*)(xg + (size_t)s.iB * 32 + cgrp * 8);
        const u32x4 cC = *(const u32x4*)(xg + (size_t)s.iC * 32 + cgrp * 8);
        const u32x4 cD = *(const u32x4*)(xg + (size_t)s.iD * 32 + cgrp * 8);
        const u32x4 bu0 = *(const u32x4*)(wgb + (size_t)(k * 2 + 0) * 512);
        const u32x4 bu1 = *(const u32x4*)(wgb + (size_t)(k * 2 + 1) * 512);

        float v[8];
#pragma unroll
        for (int qq = 0; qq < 4; ++qq) {
            v[2 * qq] = s.wA * bf16lo(cA[qq]) + s.wB * bf16lo(cB[qq]) +
                        s.wC * bf16lo(cC[qq]) + s.wD * bf16lo(cD[qq]);
            v[2 * qq + 1] = s.wA * bf16hi(cA[qq]) + s.wB * bf16hi(cB[qq]) +
                            s.wC * bf16hi(cC[qq]) + s.wD * bf16hi(cD[qq]);
        }
        const bf16x8 afr = __builtin_bit_cast(bf16x8, pack_bf16x8(v));
        acc0 = __builtin_amdgcn_mfma_f32_16x16x32_bf16(
            afr, __builtin_bit_cast(bf16x8, bu0), acc0, 0, 0, 0);
        acc1 = __builtin_amdgcn_mfma_f32_16x16x32_bf16(
            afr, __builtin_bit_cast(bf16x8, bu1), acc1, 0, 0, 0);
    }

    const int pix4 = (pt << 6) + (wave << 4) + (cgrp << 2);
#pragma unroll
    for (int nt = 0; nt < 2; ++nt) {
        const f32x4 a = nt ? acc1 : acc0;
        const int oc = g * 32 + nt * 16 + arow;
        const float bias = db[oc];
        float4 o4;
        o4.x = a[0] + bias; o4.y = a[1] + bias;
        o4.z = a[2] + bias; o4.w = a[3] + bias;
        *(float4*)&out[((size_t)b * 256 + oc) * CH_HW + pix4] = o4;
    }
}

// ===========================================================================
// Fallback path (round-4 proven, needs only 5.5 MB ws): offs_mfma + deform3
// ===========================================================================
__device__ __forceinline__ void stageA_load(const float* __restrict__ xb,
                                            int hrow, int m, int kc, int ks,
                                            float av[8])
{
    const int tap = ks >> 3, icb = ks & 7;
    const int dy = tap / 3 - 1, dx = tap % 3 - 1;
    const int sh = hrow + dy, sw = m + dx;
    const float msk = (sh >= 0 && sh < 64 && sw >= 0 && sw < 64) ? 1.f : 0.f;
    const int shc = min(max(sh, 0), 63), swc = min(max(sw, 0), 63);
    const float* p = xb + (size_t)(icb * 32 + kc * 8) * CH_HW + (shc << 6) + swc;
#pragma unroll
    for (int j = 0; j < 8; ++j) av[j] = p[(size_t)j * CH_HW] * msk;
}

__global__ __launch_bounds__(256) void offs_mfma(const float* __restrict__ x,
                                                 const __hip_bfloat16* __restrict__ wf,
                                                 const float* __restrict__ ob,
                                                 __hip_bfloat16* __restrict__ offw)
{
    __shared__ __align__(16) unsigned short aL[2][64][40];
    __shared__ __align__(16) unsigned short bL[2][2560];

    const int bid  = blockIdx.x;
    const int nh   = bid & 1;
    const int hrow = (bid >> 1) & 63;
    const int b    = bid >> 7;
    const int ntBase = nh * 5;
    const int NTLOC  = 5 - nh;
    const int tid  = threadIdx.x;
    const int lane = tid & 63, wave = tid >> 6;
    const int m    = lane;
    const int kc   = wave;

    const float* xb = x + (size_t)b * 256 * CH_HW;

    f32x4 acc[5];
#pragma unroll
    for (int q = 0; q < 5; ++q) acc[q] = (f32x4){0.f, 0.f, 0.f, 0.f};

    {
        float av[8]; u32x4 bv[2];
        stageA_load(xb, hrow, m, kc, 0, av);
#pragma unroll
        for (int q = 0; q < 2; ++q) {
            const int ntl = wave + q * 4;
            if (ntl < NTLOC)
                bv[q] = *(const u32x4*)(wf + ((size_t)(ntBase + ntl) * 64 + lane) * 8);
        }
        *(u32x4*)&aL[0][m][kc * 8] = pack_bf16x8(av);
#pragma unroll
        for (int q = 0; q < 2; ++q) {
            const int ntl = wave + q * 4;
            if (ntl < NTLOC) *(u32x4*)&bL[0][ntl * 512 + lane * 8] = bv[q];
        }
    }
    __syncthreads();

    for (int ks = 0; ks < 72; ++ks) {
        const int buf = ks & 1, nbuf = buf ^ 1;
        const bool hasNext = (ks + 1) < 72;

        float av[8]; u32x4 bv[2];
        if (hasNext) {
            stageA_load(xb, hrow, m, kc, ks + 1, av);
#pragma unroll
            for (int q = 0; q < 2; ++q) {
                const int ntl = wave + q * 4;
                if (ntl < NTLOC)
                    bv[q] = *(const u32x4*)(wf + ((size_t)((ks + 1) * 9 + ntBase + ntl) * 64 + lane) * 8);
            }
        }

        const u32x4 au = *(const u32x4*)&aL[buf][wave * 16 + (lane & 15)][(lane >> 4) * 8];
        const bf16x8 afr = __builtin_bit_cast(bf16x8, au);
#pragma unroll
        for (int ntl = 0; ntl < 5; ++ntl) {
            if (ntl < NTLOC) {
                const u32x4 bu = *(const u32x4*)&bL[buf][ntl * 512 + lane * 8];
                acc[ntl] = __builtin_amdgcn_mfma_f32_16x16x32_bf16(
                    afr, __builtin_bit_cast(bf16x8, bu), acc[ntl], 0, 0, 0);
            }
        }

        if (hasNext) {
            *(u32x4*)&aL[nbuf][m][kc * 8] = pack_bf16x8(av);
#pragma unroll
            for (int q = 0; q < 2; ++q) {
                const int ntl = wave + q * 4;
                if (ntl < NTLOC) *(u32x4*)&bL[nbuf][ntl * 512 + lane * 8] = bv[q];
            }
        }
        __syncthreads();
    }

    const int oc_l = lane & 15;
    const int mrow = wave * 16 + ((lane >> 4) << 2);
#pragma unroll
    for (int ntl = 0; ntl < 5; ++ntl) {
        if (ntl < NTLOC) {
            const int oc = (ntBase + ntl) * 16 + oc_l;
            const float bias = ob[oc];
            __hip_bfloat16* op = offw + ((size_t)b * 144 + oc) * CH_HW + hrow * 64 + mrow;
#pragma unroll
            for (int r = 0; r < 4; ++r)
                op[r] = __float2bfloat16(acc[ntl][r] + bias);
        }
    }
}

__global__ __launch_bounds__(256) void deform3(const float* __restrict__ x,
                                               const __hip_bfloat16* __restrict__ offw,
                                               const __hip_bfloat16* __restrict__ dwb,
                                               const float* __restrict__ db,
                                               float* __restrict__ out)
{
    const int pt = blockIdx.x;
    const int g  = blockIdx.y;
    const int b  = blockIdx.z;
    const int tid  = threadIdx.x;
    const int lane = tid & 63, wave = tid >> 6;
    const int pixbase = (pt << 7) + (wave << 5);
    const int arow = lane & 15;
    const int cgrp = lane >> 4;

    const float* xg = x + ((size_t)b * 256 + g * 32 + cgrp * 8) * CH_HW;
    const __hip_bfloat16* offp = offw + ((size_t)b * 144 + g * 18) * CH_HW;
    const __hip_bfloat16* wgb = dwb + (size_t)g * 9 * 2 * 512;

    f32x4 acc[2][2];
#pragma unroll
    for (int mt = 0; mt < 2; ++mt)
#pragma unroll
        for (int nt = 0; nt < 2; ++nt) acc[mt][nt] = (f32x4){0.f, 0.f, 0.f, 0.f};

#pragma unroll 1
    for (int k = 0; k < 9; ++k) {
        const u32x4 bu0 = *(const u32x4*)(wgb + (size_t)(k * 2 + 0) * 512 + lane * 8);
        const u32x4 bu1 = *(const u32x4*)(wgb + (size_t)(k * 2 + 1) * 512 + lane * 8);
        const bf16x8 bf0 = __builtin_bit_cast(bf16x8, bu0);
        const bf16x8 bf1 = __builtin_bit_cast(bf16x8, bu1);
        const int ki = k / 3, kj = k % 3;

#pragma unroll
        for (int mt = 0; mt < 2; ++mt) {
            const int pix = pixbase + mt * 16 + arow;
            const int h = pix >> 6, w = pix & 63;
            const float oy = __bfloat162float(offp[(2 * k) * CH_HW + pix]);
            const float ox = __bfloat162float(offp[(2 * k + 1) * CH_HW + pix]);
            const Samp s = make_samp((float)(h - 1 + ki) + oy,
                                     (float)(w - 1 + kj) + ox);
            float v[8];
#pragma unroll
            for (int j = 0; j < 8; ++j) {
                const float* xc = xg + (size_t)j * CH_HW;
                v[j] = s.wA * xc[s.iA] + s.wB * xc[s.iB] +
                       s.wC * xc[s.iC] + s.wD * xc[s.iD];
            }
            const bf16x8 afr = __builtin_bit_cast(bf16x8, pack_bf16x8(v));
            acc[mt][0] = __builtin_amdgcn_mfma_f32_16x16x32_bf16(afr, bf0, acc[mt][0], 0, 0, 0);
            acc[mt][1] = __builtin_amdgcn_mfma_f32_16x16x32_bf16(afr, bf1, acc[mt][1], 0, 0, 0);
        }
    }

    const int ocl = lane & 15;
#pragma unroll
    for (int mt = 0; mt < 2; ++mt)
#pragma unroll
        for (int nt = 0; nt < 2; ++nt) {
            const int oc = g * 32 + nt * 16 + ocl;
            const float bias = db[oc];
            const int pix = pixbase + mt * 16 + ((lane >> 4) << 2);
            float4 o4;
            o4.x = acc[mt][nt][0] + bias;
            o4.y = acc[mt][nt][1] + bias;
            o4.z = acc[mt][nt][2] + bias;
            o4.w = acc[mt][nt][3] + bias;
            *(float4*)&out[((size_t)b * 256 + oc) * CH_HW + pix] = o4;
        }
}

// ---------------------------------------------------------------------------
extern "C" void kernel_launch(void* const* d_in, const int* in_sizes, int n_in,
                              void* d_out, int out_size, void* d_ws, size_t ws_size,
                              hipStream_t stream) {
    const float* x  = (const float*)d_in[0];
    const float* ow = (const float*)d_in[1];
    const float* ob = (const float*)d_in[2];
    const float* dw = (const float*)d_in[3];
    const float* db = (const float*)d_in[4];
    float* out = (float*)d_out;

    __hip_bfloat16* wf   = (__hip_bfloat16*)d_ws;
    __hip_bfloat16* offw = (__hip_bfloat16*)((char*)d_ws + WF_BYTES);
    __hip_bfloat16* dwb  = (__hip_bfloat16*)((char*)d_ws + WF_BYTES + OFFW_BYTES);
    __hip_bfloat16* xt   = (__hip_bfloat16*)((char*)d_ws + WF_BYTES + OFFW_BYTES + DWB_BYTES);

    const size_t needed = (size_t)WF_BYTES + OFFW_BYTES + DWB_BYTES + XT_BYTES;

    repack_w<<<(WF_ELEMS + 255) / 256, 256, 0, stream>>>(ow, wf);
    repack_dwb<<<(DWB_ELEMS + 255) / 256, 256, 0, stream>>>(dw, dwb);

    if (ws_size >= needed) {
        xt_pack<<<dim3(16, 8, 4), 256, 0, stream>>>(x, xt);
        offs_mfma3<<<1024, 64, 0, stream>>>(xt, wf, ob, offw);
        deform5<<<dim3(64, 8, 4), 256, 0, stream>>>(xt, offw, dwb, db, out);
    } else {
        offs_mfma<<<512, 256, 0, stream>>>(x, wf, ob, offw);
        deform3<<<dim3(32, 8, 4), 256, 0, stream>>>(x, offw, dwb, db, out);
    }
}